// Round 1
// baseline (244.489 us; speedup 1.0000x reference)
//
#include <hip/hip_runtime.h>
#include <math.h>

#define BATCH 4096
#define NFEAT 4
#define VOCAB 100000
#define EMB 64
#define D_IN 256
#define D_H 256
#define D_O 128

// ---------------------------------------------------------------------------
// Gather: X[b][f*64+e] = tables[f][ids[b][f]][e], float4 per thread.
// ---------------------------------------------------------------------------
__global__ __launch_bounds__(256) void gather_kernel(
    const int* __restrict__ user_ids, const int* __restrict__ item_ids,
    const float* __restrict__ user_tables, const float* __restrict__ item_tables,
    float* __restrict__ Xu, float* __restrict__ Xi) {
  int tid = blockIdx.x * blockDim.x + threadIdx.x;  // 0 .. 2*B*64
  int which = tid / (BATCH * 64);
  int r = tid % (BATCH * 64);
  int b = r >> 6;        // batch row
  int c4 = r & 63;       // float4 slot within the 256-wide row
  int f = c4 >> 4;       // feature (16 float4 = 64 floats per feature)
  int e4 = c4 & 15;
  const int* ids = which ? item_ids : user_ids;
  const float* tbl = which ? item_tables : user_tables;
  float* X = which ? Xi : Xu;
  int id = ids[b * NFEAT + f];
  const float4* src = (const float4*)(tbl + ((size_t)f * VOCAB + (size_t)id) * EMB);
  ((float4*)(X + (size_t)b * D_IN))[c4] = src[e4];
}

// ---------------------------------------------------------------------------
// C = relu(A[M,K] @ W[K,N] + bias[N]); block tile 64x64, BK=16, 256 threads,
// 4x4 register tile per thread. blockIdx.z selects user/item pointer set.
// ---------------------------------------------------------------------------
__global__ __launch_bounds__(256) void gemm_bias_relu(
    const float* __restrict__ Au, const float* __restrict__ Ai,
    const float* __restrict__ Wu, const float* __restrict__ Wi,
    const float* __restrict__ bu, const float* __restrict__ bi,
    float* __restrict__ Cu, float* __restrict__ Ci, int K, int N) {
  const float* A; const float* W; const float* bias; float* C;
  if (blockIdx.z == 0) { A = Au; W = Wu; bias = bu; C = Cu; }
  else                 { A = Ai; W = Wi; bias = bi; C = Ci; }

  __shared__ float As[16][68];  // [kc][m], +4 pad
  __shared__ float Bs[16][68];  // [kc][n], +4 pad

  const int m0 = blockIdx.x * 64;
  const int n0 = blockIdx.y * 64;
  const int tid = threadIdx.x;
  const int tx = tid & 15;
  const int ty = tid >> 4;

  float acc[4][4] = {};

  for (int k0 = 0; k0 < K; k0 += 16) {
    {  // A tile: 64 rows x 16 k; thread: row=tid/4, kq=tid%4 loads a float4
      int row = tid >> 2, kq = tid & 3;
      float4 a = *(const float4*)(A + (size_t)(m0 + row) * K + k0 + kq * 4);
      As[kq * 4 + 0][row] = a.x;
      As[kq * 4 + 1][row] = a.y;
      As[kq * 4 + 2][row] = a.z;
      As[kq * 4 + 3][row] = a.w;
    }
    {  // B tile: 16 k x 64 n; thread: kc=tid/16, nq=tid%16 loads a float4
      int kc = tid >> 4, nq = tid & 15;
      float4 b = *(const float4*)(W + (size_t)(k0 + kc) * N + n0 + nq * 4);
      *(float4*)(&Bs[kc][nq * 4]) = b;
    }
    __syncthreads();
#pragma unroll
    for (int kc = 0; kc < 16; kc++) {
      float4 a = *(const float4*)(&As[kc][ty * 4]);
      float4 b = *(const float4*)(&Bs[kc][tx * 4]);
      float av[4] = {a.x, a.y, a.z, a.w};
      float bv[4] = {b.x, b.y, b.z, b.w};
#pragma unroll
      for (int i = 0; i < 4; i++)
#pragma unroll
        for (int j = 0; j < 4; j++) acc[i][j] += av[i] * bv[j];
    }
    __syncthreads();
  }

#pragma unroll
  for (int i = 0; i < 4; i++) {
    int m = m0 + ty * 4 + i;
#pragma unroll
    for (int j = 0; j < 4; j++) {
      int n = n0 + tx * 4 + j;
      float v = acc[i][j] + bias[n];
      C[(size_t)m * N + n] = v > 0.f ? v : 0.f;
    }
  }
}

// ---------------------------------------------------------------------------
// Scores: one wave per row i. out[i][j] = dot(u_i,v_c)/(max(|u_i|,eps)*max(|v_c|,eps))
//         - log(sw_table[sw_ids[c]]),  c=(i+j)%B
// ---------------------------------------------------------------------------
__global__ __launch_bounds__(256) void score_kernel(
    const float* __restrict__ U, const float* __restrict__ V,
    const int* __restrict__ sw_ids, const float* __restrict__ sw_table,
    float* __restrict__ out) {
  int wave = threadIdx.x >> 6;
  int lane = threadIdx.x & 63;
  int i = blockIdx.x * 4 + wave;

  float u0 = U[(size_t)i * 128 + lane];
  float u1 = U[(size_t)i * 128 + 64 + lane];
  float nu = u0 * u0 + u1 * u1;
#pragma unroll
  for (int off = 32; off; off >>= 1) nu += __shfl_xor(nu, off);
  nu = fmaxf(sqrtf(nu), 1e-8f);

#pragma unroll
  for (int j = 0; j < 4; j++) {
    int c = (i + j) & (BATCH - 1);
    float v0 = V[(size_t)c * 128 + lane];
    float v1 = V[(size_t)c * 128 + 64 + lane];
    float d = u0 * v0 + u1 * v1;
    float nv = v0 * v0 + v1 * v1;
#pragma unroll
    for (int off = 32; off; off >>= 1) {
      d += __shfl_xor(d, off);
      nv += __shfl_xor(nv, off);
    }
    nv = fmaxf(sqrtf(nv), 1e-8f);
    if (lane == 0) {
      float sw = sw_table[sw_ids[c]];
      out[(size_t)i * 4 + j] = d / (nu * nv) - logf(sw);
    }
  }
}

extern "C" void kernel_launch(void* const* d_in, const int* in_sizes, int n_in,
                              void* d_out, int out_size, void* d_ws, size_t ws_size,
                              hipStream_t stream) {
  (void)in_sizes; (void)n_in; (void)out_size; (void)ws_size;
  const int*   user_ids    = (const int*)d_in[0];
  const int*   item_ids    = (const int*)d_in[1];
  const int*   sw_ids      = (const int*)d_in[2];
  const float* user_tables = (const float*)d_in[3];
  const float* item_tables = (const float*)d_in[4];
  const float* sw_table    = (const float*)d_in[5];
  const float* uW1 = (const float*)d_in[6];
  const float* ub1 = (const float*)d_in[7];
  const float* uW2 = (const float*)d_in[8];
  const float* ub2 = (const float*)d_in[9];
  const float* iW1 = (const float*)d_in[10];
  const float* ib1 = (const float*)d_in[11];
  const float* iW2 = (const float*)d_in[12];
  const float* ib2 = (const float*)d_in[13];
  float* out = (float*)d_out;

  // workspace layout (floats)
  float* Xu = (float*)d_ws;                 // [B,256]
  float* Xi = Xu + (size_t)BATCH * D_IN;    // [B,256]
  float* Hu = Xi + (size_t)BATCH * D_IN;    // [B,256]
  float* Hi = Hu + (size_t)BATCH * D_H;     // [B,256]
  float* U  = Hi + (size_t)BATCH * D_H;     // [B,128]
  float* V  = U  + (size_t)BATCH * D_O;     // [B,128]

  // 1) gather embeddings
  gather_kernel<<<(2 * BATCH * 64) / 256, 256, 0, stream>>>(
      user_ids, item_ids, user_tables, item_tables, Xu, Xi);

  // 2) layer 1: [4096,256]@[256,256] + bias, relu (user & item)
  gemm_bias_relu<<<dim3(BATCH / 64, D_H / 64, 2), 256, 0, stream>>>(
      Xu, Xi, uW1, iW1, ub1, ib1, Hu, Hi, D_IN, D_H);

  // 3) layer 2: [4096,256]@[256,128] + bias, relu
  gemm_bias_relu<<<dim3(BATCH / 64, D_O / 64, 2), 256, 0, stream>>>(
      Hu, Hi, uW2, iW2, ub2, ib2, U, V, D_H, D_O);

  // 4) normalize + banded cosine scores - log(sw)
  score_kernel<<<BATCH / 4, 256, 0, stream>>>(U, V, sw_ids, sw_table, out);
}